// Round 7
// baseline (54.116 us; speedup 1.0000x reference)
//
#include <hip/hip_runtime.h>

// ---------------------------------------------------------------------------
// UpThreeOffsetsConvShareWeights v8: 16x16x32 MFMA for 3x occupancy.
//
// Same algebra (separable deform offsets -> per-phase 2x2x2-tap conv == GEMM
// M=spatial x N=96 x K=512; fused K=96 combine GEMM), C^T convention
// (mfma(W_frag, x_frag), lane = spatial), x direct-from-L2 (v7), drain-0
// 24KB-chunk weight ring (v5-proven), full-line float2 stores.
//
// v7 post-mortem: all pipes <25% utilized, latency-bound at 2 waves/SIMD --
// the 32x32 accumulators (96 AGPR) + osv + arch regs = ~224/wave cap TLP.
// v8: 16x16x32 MFMA, M=32/wave: acc = 2mt x 6nt x f32x4 = 48 regs, osv 16.
//  * channel-permuted W_sw/W2_sw: the main-GEMM C layout (row=4*hi+r per
//    16-ch tile) IS the combine B-frag layout (k=8*hi+j per 32-k step) by
//    construction -> epilogue = cvt_pk only, ZERO cross-lane ops.
//  * block = 4 waves x (8x,4y,4z); grid 1024 (phase-siblings co-XCD);
//    LDS = ring 48KB + bias 0.5KB -> 3 blocks/CU; launch_bounds(256,3).
//  * pipe floors: LDS-W 15.4us (binding), MFMA 12.4us, L2-x 7.8us.
// ---------------------------------------------------------------------------

typedef __bf16 bf16x8 __attribute__((ext_vector_type(8)));
typedef float f32x4 __attribute__((ext_vector_type(4)));

__device__ inline unsigned short f2bf(float f) {
  unsigned int u = __float_as_uint(f);
  u += 0x7FFFu + ((u >> 16) & 1u);
  return (unsigned short)(u >> 16);
}

__device__ inline bf16x8 bc16(uint4 v) { return __builtin_bit_cast(bf16x8, v); }

__device__ inline unsigned cvtpk(float lo, float hi) {
  unsigned r;
  asm("v_cvt_pk_bf16_f32 %0, %1, %2" : "=v"(r) : "v"(lo), "v"(hi));
  return r;
}

__device__ inline void gload16(const unsigned short* g, unsigned short* l) {
  __builtin_amdgcn_global_load_lds(
      (const __attribute__((address_space(1))) unsigned int*)(const void*)g,
      (__attribute__((address_space(3))) unsigned int*)(void*)l, 16, 0, 0);
}

__device__ inline float ucoef(int abit, int k, int jbit, float alpha) {
  if (abit == 0) return (k == 0) ? (jbit ? alpha : 1.f - alpha) : (jbit ? 1.f : 0.f);
  return (k == 2) ? (jbit ? 1.f - alpha : alpha) : (jbit ? 0.f : 1.f);
}

// xT2 geometry: 4 regions (16-ch groups), each 32768 sp * 32 B + 128 B zero tail.
#define XREG_USH 524352   // region stride in ushorts (1,048,704 B)
#define XZERO_B 1048576u  // zero-tail byte offset within a region

// ---------------- K0: all preprocessing in one kernel (2049 blocks) ---------
// W_sw (16x16x32 A-op layout, channel order n = ntile*16 + row):
//   e = ((p*16 + kstep)*6 + ntile)*512 + lane*8 + j
//   value = W[n = ntile*16 + (lane&15)][k = 32*kstep + 8*(lane>>4) + j] * s1(n)
// W2_sw: e = ((n2t*3 + ks2)*64 + lane)*8 + j
//   k2 = 32*ks2 + 8*(lane>>4) + j -> phys ch p = (2*ks2 + ((k2&7)>>2))*16
//        + 4*((k2&31)>>3) + (k2&3);  value = w_comb[n2][p] * s2(n2)
__global__ void k_prep(const float* __restrict__ x, unsigned short* __restrict__ xT2,
                       const float* __restrict__ w_def, const float* __restrict__ bn1_g,
                       const float* __restrict__ bn1_v, unsigned short* __restrict__ W_sw,
                       const float* __restrict__ w_comb, const float* __restrict__ b_comb,
                       const float* __restrict__ bn2_g, const float* __restrict__ bn2_b,
                       const float* __restrict__ bn2_m, const float* __restrict__ bn2_v,
                       const float* __restrict__ b_def, const float* __restrict__ bn1_b,
                       const float* __restrict__ bn1_m, unsigned short* __restrict__ W2_sw,
                       float* __restrict__ bias1, float* __restrict__ bias2) {
  __shared__ unsigned short t[64][65];
  int bid = blockIdx.x;
  if (bid < 512) {
    int s0 = bid * 64;
    int lane = threadIdx.x & 63;
    int grp = threadIdx.x >> 6;
#pragma unroll
    for (int c = grp; c < 64; c += 4)
      t[c][lane] = f2bf(x[c * 32768 + s0 + lane]);
    __syncthreads();
    int q = lane >> 4, e = lane & 15;  // channel = 16q + e
#pragma unroll
    for (int s = grp; s < 64; s += 4)
      xT2[q * XREG_USH + (size_t)(s0 + s) * 16 + e] = t[lane][s];
  } else if (bid < 2048) {
    int e = (bid - 512) * 256 + threadIdx.x;  // < 393216
    int j = e & 7;
    int lane = (e >> 3) & 63;
    int idx = e >> 9;          // (p*16 + kstep)*6 + ntile
    int ntile = idx % 6;
    int idx2 = idx / 6;
    int kstep = idx2 & 15;
    int p = idx2 >> 4;
    int n = ntile * 16 + (lane & 15);
    int o = n & 31, br = n >> 5;
    int k = (kstep << 5) + ((lane >> 4) << 3) + j;
    int tap = k >> 6, ch = k & 63;
    int jz = (tap >> 2) & 1, jy = (tap >> 1) & 1, jx = tap & 1;
    int a = (p >> 2) & 1, b = (p >> 1) & 1, cp = p & 1;
    float alpha = (br == 0) ? 0.f : ((br == 1) ? 0.4f : 0.7f);
    const float* wb = w_def + (o * 64 + ch) * 27;
    float sum = 0.f;
    for (int kz = 0; kz < 3; ++kz) {
      float uz = ucoef(a, kz, jz, alpha);
      if (uz == 0.f) continue;
      for (int ky = 0; ky < 3; ++ky) {
        float uy = ucoef(b, ky, jy, alpha);
        if (uy == 0.f) continue;
        float uzy = uz * uy;
        for (int kx = 0; kx < 3; ++kx) {
          float ux = ucoef(cp, kx, jx, alpha);
          if (ux != 0.f) sum += wb[kz * 9 + ky * 3 + kx] * uzy * ux;
        }
      }
    }
    float s1 = bn1_g[o] * rsqrtf(bn1_v[o] + 1e-5f);
    W_sw[e] = f2bf(sum * s1);
  } else {
    int tid = threadIdx.x;
    for (int e = tid; e < 3072; e += 256) {
      int j = e & 7;
      int lane = (e >> 3) & 63;
      int idx = e >> 9;  // n2t*3 + ks2
      int ks2 = idx % 3, n2t = idx / 3;
      int n2 = n2t * 16 + (lane & 15);
      int k2 = (ks2 << 5) + ((lane >> 4) << 3) + j;
      int pch = (2 * (k2 >> 5) + ((k2 & 7) >> 2)) * 16 + 4 * ((k2 & 31) >> 3) + (k2 & 3);
      float sc2 = bn2_g[n2] * rsqrtf(bn2_v[n2] + 1e-5f);
      W2_sw[e] = f2bf(w_comb[n2 * 96 + pch] * sc2);
    }
    // zero tails of the 4 x-regions (OOB landing pads)
    {
      int q = tid >> 6, e2 = tid & 63;
      xT2[q * XREG_USH + 524288 + e2] = 0;
    }
    if (tid < 32) {
      float s1 = bn1_g[tid] * rsqrtf(bn1_v[tid] + 1e-5f);
      bias1[tid] = (b_def[tid] - bn1_m[tid]) * s1 + bn1_b[tid];
      float s2 = bn2_g[tid] * rsqrtf(bn2_v[tid] + 1e-5f);
      bias2[tid] = (b_comb[tid] - bn2_m[tid]) * s2 + bn2_b[tid];
    }
  }
}

// ---------------- K1: main fused kernel -------------------------------------
// Grid 1024 blocks, 256 thr (4 waves). bid -> (a,bph) + (8x,4y,4z) tile,
// phase-siblings co-XCD. Wave wv = z. Per wave M=32 (2 mt(y) x 16 m), cp
// looped via chunks. m = lane&15 -> (ax = m&7, ay = m>>3); hi = lane>>4 = k/ch
// group. acc[mt][ntile] f32x4: out ch = ntile*16 + 4*hi + r, col = m.
__launch_bounds__(256, 3)
__global__ void k_main(const unsigned short* __restrict__ xT2,
                       const unsigned short* __restrict__ W_sw,
                       const unsigned short* __restrict__ W2_sw,
                       const float* __restrict__ bias1f,
                       const float* __restrict__ bias2f,
                       float* __restrict__ out) {
  __shared__ unsigned short wring[2][12288];  // 2 slots * 24 KB (2 taps each)
  __shared__ float blds[128];                 // bias1[n 0..95] | bias2[ch 0..31]
  int tid = threadIdx.x;
  int lane = tid & 63;
  int wv = tid >> 6;  // 0..3 = z within tile
  int bid = blockIdx.x;
  int tb = (bid & 7) | ((bid >> 5) << 3);  // tile 0..255
  int ph = (bid >> 3) & 3;
  int bph = ph & 1, a = ph >> 1;
  int tx = tb & 3, ty = (tb >> 2) & 7, tz = tb >> 5;
  int i0 = tz * 4, j0 = ty * 4, k0 = tx * 8;

  if (tid < 96) blds[tid] = bias1f[tid & 31];
  else if (tid < 128) blds[tid] = bias2f[tid - 96];

  int m = lane & 15, hi = lane >> 4;
  int ax = m & 7, ay = m >> 3;
  int p0 = (a << 2) | (bph << 1);
  // per-lane x region base: region (hi>>1) (+2 for khalf=1), sub-off (hi&1)*16
  const char* xb0 = (const char*)xT2 + (size_t)(hi >> 1) * 1048704 + ((hi & 1) << 4);

  // chunk cc (0..7): phase p0|(cc>>2), k-steps 4(cc&3)..+3 (= taps 2(cc&3),+1),
  // 24576 B. 4 waves x 6144 B each = 6 x width-16 wave-instructions.
  auto stage = [&](int cc) {
    int pn = p0 | (cc >> 2);
    const unsigned short* g =
        W_sw + pn * 49152 + (cc & 3) * 12288 + wv * 3072 + lane * 8;
    unsigned short* l = &wring[cc & 1][wv * 3072];
#pragma unroll
    for (int k = 0; k < 6; ++k) gload16(g + k * 512, l + k * 512);
  };

  __syncthreads();  // blds visible before loop barriers
  stage(0);

  const f32x4* b1v = (const f32x4*)blds;         // [ntile*4 + hi]
  const f32x4* b2v = (const f32x4*)(blds + 96);  // [n2t*4 + hi]
  const uint4* w2q = (const uint4*)W2_sw;

  f32x4 osv[2][2];  // cp=0 final outputs, held across cp=1
  f32x4 acc[2][6];
#pragma unroll
  for (int mt = 0; mt < 2; ++mt)
#pragma unroll
    for (int nt = 0; nt < 6; ++nt) acc[mt][nt] = (f32x4)0.f;

  for (int cc = 0; cc < 8; ++cc) {
    asm volatile("s_waitcnt vmcnt(0)" ::: "memory");  // own chunk-cc loads in
    __builtin_amdgcn_s_barrier();                     // all waves' parts in
    __builtin_amdgcn_sched_barrier(0);
    if (cc < 7) stage(cc + 1);  // next chunk flies during this chunk's work
    __builtin_amdgcn_sched_barrier(0);

    int cp = cc >> 2;
    // x offsets for the chunk's 2 taps x 2 mt (OOB -> zero tail)
    unsigned xoff[2][2];
#pragma unroll
    for (int tl = 0; tl < 2; ++tl) {
      int tap = 2 * (cc & 3) + tl;
      int jz = (tap >> 2) & 1, jy = (tap >> 1) & 1, jx = tap & 1;
      int gz = i0 + wv + a - 1 + jz;
      int gx = k0 + ax + cp - 1 + jx;
#pragma unroll
      for (int mt = 0; mt < 2; ++mt) {
        int gy = j0 + 2 * mt + ay + bph - 1 + jy;
        bool ok = ((unsigned)gz < 32u) && ((unsigned)gy < 32u) && ((unsigned)gx < 32u);
        unsigned off = (unsigned)(((gz * 32 + gy) * 32 + gx) * 32);
        xoff[tl][mt] = ok ? off : XZERO_B;
      }
    }

    const unsigned short* wcb = &wring[cc & 1][lane * 8];
#pragma unroll
    for (int ksl = 0; ksl < 4; ++ksl) {  // k-step within chunk
      int tl = ksl >> 1, khalf = ksl & 1;
      const char* xp = xb0 + khalf * 2097408;
      bf16x8 x0 = bc16(*(const uint4*)(xp + xoff[tl][0]));
      bf16x8 x1 = bc16(*(const uint4*)(xp + xoff[tl][1]));
      const unsigned short* wk = wcb + ksl * 3072;
      bf16x8 w0 = bc16(*(const uint4*)(wk));
      bf16x8 w1 = bc16(*(const uint4*)(wk + 512));
      bf16x8 w2 = bc16(*(const uint4*)(wk + 1024));
      bf16x8 w3 = bc16(*(const uint4*)(wk + 1536));
      bf16x8 w4 = bc16(*(const uint4*)(wk + 2048));
      bf16x8 w5 = bc16(*(const uint4*)(wk + 2560));
      __builtin_amdgcn_s_setprio(1);
      acc[0][0] = __builtin_amdgcn_mfma_f32_16x16x32_bf16(w0, x0, acc[0][0], 0, 0, 0);
      acc[1][0] = __builtin_amdgcn_mfma_f32_16x16x32_bf16(w0, x1, acc[1][0], 0, 0, 0);
      acc[0][1] = __builtin_amdgcn_mfma_f32_16x16x32_bf16(w1, x0, acc[0][1], 0, 0, 0);
      acc[1][1] = __builtin_amdgcn_mfma_f32_16x16x32_bf16(w1, x1, acc[1][1], 0, 0, 0);
      acc[0][2] = __builtin_amdgcn_mfma_f32_16x16x32_bf16(w2, x0, acc[0][2], 0, 0, 0);
      acc[1][2] = __builtin_amdgcn_mfma_f32_16x16x32_bf16(w2, x1, acc[1][2], 0, 0, 0);
      acc[0][3] = __builtin_amdgcn_mfma_f32_16x16x32_bf16(w3, x0, acc[0][3], 0, 0, 0);
      acc[1][3] = __builtin_amdgcn_mfma_f32_16x16x32_bf16(w3, x1, acc[1][3], 0, 0, 0);
      acc[0][4] = __builtin_amdgcn_mfma_f32_16x16x32_bf16(w4, x0, acc[0][4], 0, 0, 0);
      acc[1][4] = __builtin_amdgcn_mfma_f32_16x16x32_bf16(w4, x1, acc[1][4], 0, 0, 0);
      acc[0][5] = __builtin_amdgcn_mfma_f32_16x16x32_bf16(w5, x0, acc[0][5], 0, 0, 0);
      acc[1][5] = __builtin_amdgcn_mfma_f32_16x16x32_bf16(w5, x1, acc[1][5], 0, 0, 0);
      __builtin_amdgcn_s_setprio(0);
    }

    if (cc == 3) {
      // ---- cp=0 epilogue: BN1+ReLU+pack (lane-local!), combine, BN2+ReLU ----
#pragma unroll
      for (int mt = 0; mt < 2; ++mt) {
        uint4 fr[3];
#pragma unroll
        for (int ks2 = 0; ks2 < 3; ++ks2) {
          f32x4 vA = acc[mt][2 * ks2], vB = acc[mt][2 * ks2 + 1];
          f32x4 bA = b1v[(2 * ks2) * 4 + hi], bB = b1v[(2 * ks2 + 1) * 4 + hi];
          fr[ks2] = make_uint4(
              cvtpk(fmaxf(vA[0] + bA[0], 0.f), fmaxf(vA[1] + bA[1], 0.f)),
              cvtpk(fmaxf(vA[2] + bA[2], 0.f), fmaxf(vA[3] + bA[3], 0.f)),
              cvtpk(fmaxf(vB[0] + bB[0], 0.f), fmaxf(vB[1] + bB[1], 0.f)),
              cvtpk(fmaxf(vB[2] + bB[2], 0.f), fmaxf(vB[3] + bB[3], 0.f)));
        }
        f32x4 a20 = (f32x4)0.f, a21 = (f32x4)0.f;
#pragma unroll
        for (int ks2 = 0; ks2 < 3; ++ks2) {
          a20 = __builtin_amdgcn_mfma_f32_16x16x32_bf16(bc16(w2q[ks2 * 64 + lane]),
                                                        bc16(fr[ks2]), a20, 0, 0, 0);
          a21 = __builtin_amdgcn_mfma_f32_16x16x32_bf16(bc16(w2q[(3 + ks2) * 64 + lane]),
                                                        bc16(fr[ks2]), a21, 0, 0, 0);
        }
        f32x4 b20 = b2v[hi], b21 = b2v[4 + hi];
#pragma unroll
        for (int r = 0; r < 4; ++r) {
          osv[mt][0][r] = fmaxf(a20[r] + b20[r], 0.f);
          osv[mt][1][r] = fmaxf(a21[r] + b21[r], 0.f);
        }
#pragma unroll
        for (int nt = 0; nt < 6; ++nt) acc[mt][nt] = (f32x4)0.f;
      }
    }
  }

  // ---- cp=1 epilogue + full-line float2 stores ----
#pragma unroll
  for (int mt = 0; mt < 2; ++mt) {
    uint4 fr[3];
#pragma unroll
    for (int ks2 = 0; ks2 < 3; ++ks2) {
      f32x4 vA = acc[mt][2 * ks2], vB = acc[mt][2 * ks2 + 1];
      f32x4 bA = b1v[(2 * ks2) * 4 + hi], bB = b1v[(2 * ks2 + 1) * 4 + hi];
      fr[ks2] = make_uint4(
          cvtpk(fmaxf(vA[0] + bA[0], 0.f), fmaxf(vA[1] + bA[1], 0.f)),
          cvtpk(fmaxf(vA[2] + bA[2], 0.f), fmaxf(vA[3] + bA[3], 0.f)),
          cvtpk(fmaxf(vB[0] + bB[0], 0.f), fmaxf(vB[1] + bB[1], 0.f)),
          cvtpk(fmaxf(vB[2] + bB[2], 0.f), fmaxf(vB[3] + bB[3], 0.f)));
    }
    f32x4 a20 = (f32x4)0.f, a21 = (f32x4)0.f;
#pragma unroll
    for (int ks2 = 0; ks2 < 3; ++ks2) {
      a20 = __builtin_amdgcn_mfma_f32_16x16x32_bf16(bc16(w2q[ks2 * 64 + lane]),
                                                    bc16(fr[ks2]), a20, 0, 0, 0);
      a21 = __builtin_amdgcn_mfma_f32_16x16x32_bf16(bc16(w2q[(3 + ks2) * 64 + lane]),
                                                    bc16(fr[ks2]), a21, 0, 0, 0);
    }
    f32x4 b20 = b2v[hi], b21 = b2v[4 + hi];
    int Z = 2 * (i0 + wv) + a;
    int Y = 2 * (j0 + 2 * mt + ay) + bph;
    size_t sb = ((size_t)Z << 11) + (Y << 5) + (k0 + ax);
    float2* o2 = (float2*)out;
#pragma unroll
    for (int r = 0; r < 4; ++r) {
      int ch0 = 4 * hi + r, ch1 = 16 + 4 * hi + r;
      o2[((size_t)ch0 << 17) + sb] =
          make_float2(osv[mt][0][r], fmaxf(a20[r] + b20[r], 0.f));
      o2[((size_t)ch1 << 17) + sb] =
          make_float2(osv[mt][1][r], fmaxf(a21[r] + b21[r], 0.f));
    }
  }
}

// ---------------------------------------------------------------------------
extern "C" void kernel_launch(void* const* d_in, const int* in_sizes, int n_in,
                              void* d_out, int out_size, void* d_ws, size_t ws_size,
                              hipStream_t stream) {
  (void)in_sizes; (void)n_in; (void)out_size; (void)ws_size;
  const float* x      = (const float*)d_in[0];
  const float* w_def  = (const float*)d_in[1];
  const float* b_def  = (const float*)d_in[2];
  const float* bn1_g  = (const float*)d_in[3];
  const float* bn1_b  = (const float*)d_in[4];
  const float* bn1_m  = (const float*)d_in[5];
  const float* bn1_v  = (const float*)d_in[6];
  const float* w_comb = (const float*)d_in[7];
  const float* b_comb = (const float*)d_in[8];
  const float* bn2_g  = (const float*)d_in[9];
  const float* bn2_b  = (const float*)d_in[10];
  const float* bn2_m  = (const float*)d_in[11];
  const float* bn2_v  = (const float*)d_in[12];

  char* ws = (char*)d_ws;
  unsigned short* xT2  = (unsigned short*)(ws);             // 4,194,816 B
  unsigned short* W_sw = (unsigned short*)(ws + 4194816);   //   786,432 B
  unsigned short* W2sw = (unsigned short*)(ws + 4981248);   //     6,144 B
  float* bias1 = (float*)(ws + 4987392);                    //       128 B
  float* bias2 = (float*)(ws + 4987520);                    //       128 B
  float* out = (float*)d_out;

  hipLaunchKernelGGL(k_prep, dim3(2049), dim3(256), 0, stream,
                     x, xT2, w_def, bn1_g, bn1_v, W_sw,
                     w_comb, b_comb, bn2_g, bn2_b, bn2_m, bn2_v,
                     b_def, bn1_b, bn1_m, W2sw, bias1, bias2);
  hipLaunchKernelGGL(k_main, dim3(1024), dim3(256), 0, stream,
                     xT2, W_sw, W2sw, bias1, bias2, out);
}